// Round 1
// baseline (391.132 us; speedup 1.0000x reference)
//
#include <hip/hip_runtime.h>
#include <hip/hip_bf16.h>

// Problem constants
#define TOKENS 2048      // B*S
#define DMODEL 1024
#define NEXP 8
#define TOPK 2
#define FFDIM 2048
#define MAXSLOTS 5120    // sum of per-expert 128-padded counts <= 4096 + 8*127 = 5112

typedef __bf16 bf16_t;
typedef __bf16 bf16x8 __attribute__((ext_vector_type(8)));
typedef float f32x4 __attribute__((ext_vector_type(4)));

// d_out layout (floats): output | router_probs | topk_indices | topk_weights
#define OUT_PROBS (TOKENS * DMODEL)            // 2097152
#define OUT_IDX (OUT_PROBS + TOKENS * NEXP)    // 2113536
#define OUT_W (OUT_IDX + TOKENS * TOPK)        // 2117632

// ws layout (bytes)
#define WS_TOKE 0                              // int[4096]
#define WS_TOKW 16384                          // float[4096]
#define WS_OFFS 32768                          // int[16]
#define WS_ROWTOK 33024                        // int[5120]
#define WS_SLOTOF 73984                        // int[4096]
#define WS_H 98304                             // bf16 [5120][2048]  (20971520 B)
#define WS_Y (98304 + (size_t)MAXSLOTS * FFDIM * 2)  // f32 [5120][1024]

// ---------------- Router: logits, softmax, top-2, renorm ----------------
__global__ void k_router(const float* __restrict__ x, const float* __restrict__ rw,
                         float* __restrict__ out, int* __restrict__ tok_e,
                         float* __restrict__ tok_w) {
    __shared__ float s_rw[NEXP * DMODEL];  // 32 KB
    const float4* rw4 = (const float4*)rw;
    float4* s4 = (float4*)s_rw;
#pragma unroll
    for (int i = 0; i < (NEXP * DMODEL / 4) / 256; ++i)
        s4[i * 256 + threadIdx.x] = rw4[i * 256 + threadIdx.x];
    __syncthreads();

    const int wave = threadIdx.x >> 6;
    const int lane = threadIdx.x & 63;
    const int t = blockIdx.x * 4 + wave;  // one wave per token

    float acc[NEXP];
#pragma unroll
    for (int e = 0; e < NEXP; ++e) acc[e] = 0.f;
    for (int j = 0; j < DMODEL / 64; ++j) {
        float xv = x[(size_t)t * DMODEL + j * 64 + lane];
#pragma unroll
        for (int e = 0; e < NEXP; ++e) acc[e] += xv * s_rw[e * DMODEL + j * 64 + lane];
    }
#pragma unroll
    for (int off = 32; off > 0; off >>= 1) {
#pragma unroll
        for (int e = 0; e < NEXP; ++e) acc[e] += __shfl_xor(acc[e], off);
    }

    if (lane == 0) {
        float m = acc[0];
#pragma unroll
        for (int e = 1; e < NEXP; ++e) m = fmaxf(m, acc[e]);
        float p[NEXP];
        float sum = 0.f;
#pragma unroll
        for (int e = 0; e < NEXP; ++e) { p[e] = expf(acc[e] - m); sum += p[e]; }
#pragma unroll
        for (int e = 0; e < NEXP; ++e) p[e] = p[e] / sum;
        // top-2, ties -> lower index (strictly-greater scans)
        int i0 = 0;
#pragma unroll
        for (int e = 1; e < NEXP; ++e) if (p[e] > p[i0]) i0 = e;
        int i1 = (i0 == 0) ? 1 : 0;
#pragma unroll
        for (int e = 0; e < NEXP; ++e) if (e != i0 && p[e] > p[i1]) i1 = e;
        float w0 = p[i0], w1 = p[i1];
        float s2 = w0 + w1;
        float w0n = w0 / s2, w1n = w1 / s2;
#pragma unroll
        for (int e = 0; e < NEXP; ++e) out[OUT_PROBS + (size_t)t * NEXP + e] = p[e];
        out[OUT_IDX + (size_t)t * TOPK + 0] = (float)i0;
        out[OUT_IDX + (size_t)t * TOPK + 1] = (float)i1;
        out[OUT_W + (size_t)t * TOPK + 0] = w0n;
        out[OUT_W + (size_t)t * TOPK + 1] = w1n;
        tok_e[t * 2 + 0] = i0;
        tok_e[t * 2 + 1] = i1;
        tok_w[t * 2 + 0] = w0n;
        tok_w[t * 2 + 1] = w1n;
    }
}

// ---------------- Finalize: histogram, 128-padded offsets, slot assignment ----------------
__global__ void k_finalize(const int* __restrict__ tok_e, const float* __restrict__ tok_w,
                           int* __restrict__ offs, int* __restrict__ row_tok,
                           int* __restrict__ slot_of) {
    __shared__ int cnt[NEXP];
    __shared__ int fill[NEXP];
    __shared__ int soff[NEXP + 1];
    const int tid = threadIdx.x;
    if (tid < NEXP) { cnt[tid] = 0; fill[tid] = 0; }
    __syncthreads();
    for (int i = tid; i < TOKENS * 2; i += 256) atomicAdd(&cnt[tok_e[i]], 1);
    __syncthreads();
    if (tid == 0) {
        int o = 0;
        for (int e = 0; e < NEXP; ++e) {
            soff[e] = o;
            o += (cnt[e] + 127) & ~127;  // pad to tile multiple: tiles never straddle experts
        }
        soff[NEXP] = o;
    }
    __syncthreads();
    if (tid <= NEXP) offs[tid] = soff[tid];
    // init all slots invalid, then fill
    for (int i = tid; i < MAXSLOTS; i += 256) row_tok[i] = -1;
    __syncthreads();
    for (int i = tid; i < TOKENS * 2; i += 256) {
        int e = tok_e[i];
        int pos = atomicAdd(&fill[e], 1);
        int slot = soff[e] + pos;
        row_tok[slot] = i >> 1;
        slot_of[i] = slot;
    }
}

// LDS 16B-slot swizzle: per row of 4 slots, rotate by (r>>1) so a 16-lane
// fragment-read phase covers each bank exactly 2x (2-way = free).
__device__ __forceinline__ int lds16(int r, int s) { return r * 4 + ((s + (r >> 1)) & 3); }

// ---------------- GEMM1: H = silu(x_gathered @ w1_e^T), bf16 MFMA ----------------
__global__ void k_gemm1(const float* __restrict__ x, const float* __restrict__ w1,
                        const int* __restrict__ offs, const int* __restrict__ row_tok,
                        bf16_t* __restrict__ H) {
    const int e = blockIdx.z;
    const int off = offs[e];
    const int npad = offs[e + 1] - off;
    const int m0 = blockIdx.y * 128;
    if (m0 >= npad) return;
    const int n0 = blockIdx.x * 128;

    __shared__ __align__(16) bf16_t As[128 * 32];
    __shared__ __align__(16) bf16_t Bs[128 * 32];
    __shared__ int rtok[128];

    const int tid = threadIdx.x;
    if (tid < 128) rtok[tid] = row_tok[off + m0 + tid];
    __syncthreads();

    const int wid = tid >> 6, lane = tid & 63;
    const int wr = wid >> 1, wc = wid & 1;
    const int lr = lane & 15, ls = lane >> 4;

    f32x4 acc[4][4];
#pragma unroll
    for (int mi = 0; mi < 4; ++mi)
#pragma unroll
        for (int ni = 0; ni < 4; ++ni) acc[mi][ni] = (f32x4){0.f, 0.f, 0.f, 0.f};

    const int r = tid >> 1;             // staging row (2 threads per row)
    const int scol = (tid & 1) * 16;    // starting float within the 32-wide k-slab
    const int rsh = (r >> 1);
    const int tA = rtok[r];             // gathered token for A row (or -1 padding)

    float4 ar[4], br[4];
    const int NK = DMODEL / 32;

    // prologue loads (k-step 0)
    {
        if (tA >= 0) {
            const float4* p = (const float4*)(x + (size_t)tA * DMODEL + scol);
#pragma unroll
            for (int q = 0; q < 4; ++q) ar[q] = p[q];
        } else {
#pragma unroll
            for (int q = 0; q < 4; ++q) ar[q] = (float4){0.f, 0.f, 0.f, 0.f};
        }
        const float4* p = (const float4*)(w1 + ((size_t)e * FFDIM + n0 + r) * DMODEL + scol);
#pragma unroll
        for (int q = 0; q < 4; ++q) br[q] = p[q];
    }

    for (int kt = 0; kt < NK; ++kt) {
        // ds_write staged regs (convert f32 -> bf16), swizzled
#pragma unroll
        for (int j = 0; j < 2; ++j) {
            int s = (tid & 1) * 2 + j;
            int oA = lds16(r, s);
            bf16x8 v;
            float4 u0 = ar[j * 2], u1 = ar[j * 2 + 1];
            v[0] = (bf16_t)u0.x; v[1] = (bf16_t)u0.y; v[2] = (bf16_t)u0.z; v[3] = (bf16_t)u0.w;
            v[4] = (bf16_t)u1.x; v[5] = (bf16_t)u1.y; v[6] = (bf16_t)u1.z; v[7] = (bf16_t)u1.w;
            *(bf16x8*)&As[oA * 8] = v;
            float4 t0 = br[j * 2], t1 = br[j * 2 + 1];
            bf16x8 w;
            w[0] = (bf16_t)t0.x; w[1] = (bf16_t)t0.y; w[2] = (bf16_t)t0.z; w[3] = (bf16_t)t0.w;
            w[4] = (bf16_t)t1.x; w[5] = (bf16_t)t1.y; w[6] = (bf16_t)t1.z; w[7] = (bf16_t)t1.w;
            *(bf16x8*)&Bs[oA * 8] = w;
        }
        __syncthreads();
        // issue next-tile global loads early (latency hides under MFMA)
        if (kt + 1 < NK) {
            int k0 = (kt + 1) * 32;
            if (tA >= 0) {
                const float4* p = (const float4*)(x + (size_t)tA * DMODEL + k0 + scol);
#pragma unroll
                for (int q = 0; q < 4; ++q) ar[q] = p[q];
            } else {
#pragma unroll
                for (int q = 0; q < 4; ++q) ar[q] = (float4){0.f, 0.f, 0.f, 0.f};
            }
            const float4* p = (const float4*)(w1 + ((size_t)e * FFDIM + n0 + r) * DMODEL + k0 + scol);
#pragma unroll
            for (int q = 0; q < 4; ++q) br[q] = p[q];
        }
        // compute
        bf16x8 af[4], bfr[4];
#pragma unroll
        for (int mi = 0; mi < 4; ++mi) {
            int rr = wr * 64 + mi * 16 + lr;
            af[mi] = *(const bf16x8*)&As[lds16(rr, ls) * 8];
        }
#pragma unroll
        for (int ni = 0; ni < 4; ++ni) {
            int rr = wc * 64 + ni * 16 + lr;
            bfr[ni] = *(const bf16x8*)&Bs[lds16(rr, ls) * 8];
        }
#pragma unroll
        for (int mi = 0; mi < 4; ++mi)
#pragma unroll
            for (int ni = 0; ni < 4; ++ni)
                acc[mi][ni] = __builtin_amdgcn_mfma_f32_16x16x32_bf16(af[mi], bfr[ni], acc[mi][ni], 0, 0, 0);
        __syncthreads();
    }

    // epilogue: SiLU, store bf16 H  (C/D map: col=lane&15, row=(lane>>4)*4+reg)
#pragma unroll
    for (int mi = 0; mi < 4; ++mi) {
#pragma unroll
        for (int ni = 0; ni < 4; ++ni) {
            int rowL = wr * 64 + mi * 16 + ls * 4;
            int colL = wc * 64 + ni * 16 + lr;
#pragma unroll
            for (int v = 0; v < 4; ++v) {
                float val = acc[mi][ni][v];
                float sv = val / (1.f + expf(-val));
                H[(size_t)(off + m0 + rowL + v) * FFDIM + n0 + colL] = (bf16_t)sv;
            }
        }
    }
}

// ---------------- GEMM2: Y = H @ w2_e^T, f32 out ----------------
__global__ void k_gemm2(const bf16_t* __restrict__ H, const float* __restrict__ w2,
                        const int* __restrict__ offs, float* __restrict__ Y) {
    const int e = blockIdx.z;
    const int off = offs[e];
    const int npad = offs[e + 1] - off;
    const int m0 = blockIdx.y * 128;
    if (m0 >= npad) return;
    const int n0 = blockIdx.x * 128;

    __shared__ __align__(16) bf16_t As[128 * 32];
    __shared__ __align__(16) bf16_t Bs[128 * 32];

    const int tid = threadIdx.x;
    const int wid = tid >> 6, lane = tid & 63;
    const int wr = wid >> 1, wc = wid & 1;
    const int lr = lane & 15, ls = lane >> 4;

    f32x4 acc[4][4];
#pragma unroll
    for (int mi = 0; mi < 4; ++mi)
#pragma unroll
        for (int ni = 0; ni < 4; ++ni) acc[mi][ni] = (f32x4){0.f, 0.f, 0.f, 0.f};

    const int r = tid >> 1;
    const int scol = (tid & 1) * 16;  // element offset within 32-wide k-slab
    const int NK = FFDIM / 32;

    float4 a2[2];  // 16 bf16 raw bits
    float4 br[4];
    {
        const float4* pa = (const float4*)(H + (size_t)(off + m0 + r) * FFDIM + scol);
        a2[0] = pa[0]; a2[1] = pa[1];
        const float4* pb = (const float4*)(w2 + ((size_t)e * DMODEL + n0 + r) * FFDIM + scol);
#pragma unroll
        for (int q = 0; q < 4; ++q) br[q] = pb[q];
    }

    for (int kt = 0; kt < NK; ++kt) {
#pragma unroll
        for (int j = 0; j < 2; ++j) {
            int s = (tid & 1) * 2 + j;
            int o16 = lds16(r, s);
            *(float4*)&As[o16 * 8] = a2[j];  // already bf16 bits
            float4 t0 = br[j * 2], t1 = br[j * 2 + 1];
            bf16x8 w;
            w[0] = (bf16_t)t0.x; w[1] = (bf16_t)t0.y; w[2] = (bf16_t)t0.z; w[3] = (bf16_t)t0.w;
            w[4] = (bf16_t)t1.x; w[5] = (bf16_t)t1.y; w[6] = (bf16_t)t1.z; w[7] = (bf16_t)t1.w;
            *(bf16x8*)&Bs[o16 * 8] = w;
        }
        __syncthreads();
        if (kt + 1 < NK) {
            int k0 = (kt + 1) * 32;
            const float4* pa = (const float4*)(H + (size_t)(off + m0 + r) * FFDIM + k0 + scol);
            a2[0] = pa[0]; a2[1] = pa[1];
            const float4* pb = (const float4*)(w2 + ((size_t)e * DMODEL + n0 + r) * FFDIM + k0 + scol);
#pragma unroll
            for (int q = 0; q < 4; ++q) br[q] = pb[q];
        }
        bf16x8 af[4], bfr[4];
#pragma unroll
        for (int mi = 0; mi < 4; ++mi) {
            int rr = wr * 64 + mi * 16 + lr;
            af[mi] = *(const bf16x8*)&As[lds16(rr, ls) * 8];
        }
#pragma unroll
        for (int ni = 0; ni < 4; ++ni) {
            int rr = wc * 64 + ni * 16 + lr;
            bfr[ni] = *(const bf16x8*)&Bs[lds16(rr, ls) * 8];
        }
#pragma unroll
        for (int mi = 0; mi < 4; ++mi)
#pragma unroll
            for (int ni = 0; ni < 4; ++ni)
                acc[mi][ni] = __builtin_amdgcn_mfma_f32_16x16x32_bf16(af[mi], bfr[ni], acc[mi][ni], 0, 0, 0);
        __syncthreads();
    }

#pragma unroll
    for (int mi = 0; mi < 4; ++mi) {
#pragma unroll
        for (int ni = 0; ni < 4; ++ni) {
            int rowL = wr * 64 + mi * 16 + ls * 4;
            int colL = wc * 64 + ni * 16 + lr;
#pragma unroll
            for (int v = 0; v < 4; ++v) {
                Y[(size_t)(off + m0 + rowL + v) * DMODEL + n0 + colL] = acc[mi][ni][v];
            }
        }
    }
}

// ---------------- Combine: out[t] = w0*Y[s0] + w1*Y[s1] (deterministic, no atomics) ----------------
__global__ void k_combine(const float* __restrict__ Y, const int* __restrict__ slot_of,
                          const float* __restrict__ tok_w, float* __restrict__ out) {
    const int t = blockIdx.x;
    const int d = threadIdx.x;  // 256 threads * float4 = 1024
    int s0 = slot_of[t * 2 + 0], s1 = slot_of[t * 2 + 1];
    float w0 = tok_w[t * 2 + 0], w1 = tok_w[t * 2 + 1];
    float4 y0 = ((const float4*)(Y + (size_t)s0 * DMODEL))[d];
    float4 y1 = ((const float4*)(Y + (size_t)s1 * DMODEL))[d];
    float4 o;
    o.x = w0 * y0.x + w1 * y1.x;
    o.y = w0 * y0.y + w1 * y1.y;
    o.z = w0 * y0.z + w1 * y1.z;
    o.w = w0 * y0.w + w1 * y1.w;
    ((float4*)(out + (size_t)t * DMODEL))[d] = o;
}

extern "C" void kernel_launch(void* const* d_in, const int* in_sizes, int n_in,
                              void* d_out, int out_size, void* d_ws, size_t ws_size,
                              hipStream_t stream) {
    const float* x = (const float*)d_in[0];
    const float* rw = (const float*)d_in[1];
    const float* w1 = (const float*)d_in[2];
    const float* w2 = (const float*)d_in[3];
    float* out = (float*)d_out;
    char* ws = (char*)d_ws;

    int* tok_e = (int*)(ws + WS_TOKE);
    float* tok_w = (float*)(ws + WS_TOKW);
    int* offs = (int*)(ws + WS_OFFS);
    int* row_tok = (int*)(ws + WS_ROWTOK);
    int* slot_of = (int*)(ws + WS_SLOTOF);
    bf16_t* H = (bf16_t*)(ws + WS_H);
    float* Yb = (float*)(ws + WS_Y);

    k_router<<<TOKENS / 4, 256, 0, stream>>>(x, rw, out, tok_e, tok_w);
    k_finalize<<<1, 256, 0, stream>>>(tok_e, tok_w, offs, row_tok, slot_of);
    k_gemm1<<<dim3(FFDIM / 128, 16, NEXP), 256, 0, stream>>>(x, w1, offs, row_tok, H);
    k_gemm2<<<dim3(DMODEL / 128, 16, NEXP), 256, 0, stream>>>(H, w2, offs, Yb);
    k_combine<<<TOKENS, 256, 0, stream>>>(Yb, slot_of, tok_w, out);
}

// Round 2
// 357.861 us; speedup vs baseline: 1.0930x; 1.0930x over previous
//
#include <hip/hip_runtime.h>
#include <hip/hip_bf16.h>

// Problem constants
#define TOKENS 2048      // B*S
#define DMODEL 1024
#define NEXP 8
#define TOPK 2
#define FFDIM 2048
#define MAXSLOTS 5120    // sum of per-expert 128-padded counts <= 4096 + 8*127 = 5112
#define MTILES (MAXSLOTS / 128)   // 40

typedef __bf16 bf16_t;
typedef __bf16 bf16x8 __attribute__((ext_vector_type(8)));
typedef float f32x4 __attribute__((ext_vector_type(4)));

// d_out layout (floats): output | router_probs | topk_indices | topk_weights
#define OUT_PROBS (TOKENS * DMODEL)            // 2097152
#define OUT_IDX (OUT_PROBS + TOKENS * NEXP)    // 2113536
#define OUT_W (OUT_IDX + TOKENS * TOPK)        // 2117632

// ws layout (bytes)
#define WS_TOKE 0                              // int[4096]
#define WS_TOKW 16384                          // float[4096]
#define WS_OFFS 32768                          // int[16]
#define WS_ROWTOK 33024                        // int[5120] -> ends 53504
#define WS_SLOTW 57344                         // float[5120] -> ends 77824
#define WS_H 98304                             // bf16 [5120][2048]  (20971520 B)

// LDS row stride: 32 k-elems + 8 pad = 40 bf16 (80 B). 16-lane fragment reads
// at fixed 16B col across rows hit 8 distinct 16B bank-groups x 2 lanes = free.
#define LDSW 40

// ---------------- Router: logits, softmax, top-2, renorm ----------------
__global__ __launch_bounds__(256) void k_router(
        const float* __restrict__ x, const float* __restrict__ rw,
        float* __restrict__ out, int* __restrict__ tok_e, float* __restrict__ tok_w) {
    __shared__ float s_rw[NEXP * DMODEL];  // 32 KB
    const float4* rw4 = (const float4*)rw;
    float4* s4 = (float4*)s_rw;
#pragma unroll
    for (int i = 0; i < (NEXP * DMODEL / 4) / 256; ++i)
        s4[i * 256 + threadIdx.x] = rw4[i * 256 + threadIdx.x];
    __syncthreads();

    const int wave = threadIdx.x >> 6;
    const int lane = threadIdx.x & 63;
    const int t = blockIdx.x * 4 + wave;  // one wave per token

    float acc[NEXP];
#pragma unroll
    for (int e = 0; e < NEXP; ++e) acc[e] = 0.f;
    const float4* xr = (const float4*)(x + (size_t)t * DMODEL);
#pragma unroll
    for (int j = 0; j < DMODEL / 256; ++j) {  // 4 steps, float4 per lane
        float4 xv = xr[j * 64 + lane];
#pragma unroll
        for (int e = 0; e < NEXP; ++e) {
            const float4 rv = *(const float4*)&s_rw[e * DMODEL + (j * 64 + lane) * 4];
            acc[e] += xv.x * rv.x + xv.y * rv.y + xv.z * rv.z + xv.w * rv.w;
        }
    }
#pragma unroll
    for (int off = 32; off > 0; off >>= 1) {
#pragma unroll
        for (int e = 0; e < NEXP; ++e) acc[e] += __shfl_xor(acc[e], off);
    }

    if (lane == 0) {
        float m = acc[0];
#pragma unroll
        for (int e = 1; e < NEXP; ++e) m = fmaxf(m, acc[e]);
        float p[NEXP];
        float sum = 0.f;
#pragma unroll
        for (int e = 0; e < NEXP; ++e) { p[e] = expf(acc[e] - m); sum += p[e]; }
#pragma unroll
        for (int e = 0; e < NEXP; ++e) p[e] = p[e] / sum;
        // top-2, ties -> lower index (strictly-greater scans)
        int i0 = 0;
#pragma unroll
        for (int e = 1; e < NEXP; ++e) if (p[e] > p[i0]) i0 = e;
        int i1 = (i0 == 0) ? 1 : 0;
#pragma unroll
        for (int e = 0; e < NEXP; ++e) if (e != i0 && p[e] > p[i1]) i1 = e;
        float w0 = p[i0], w1 = p[i1];
        float s2 = w0 + w1;
        float w0n = w0 / s2, w1n = w1 / s2;
#pragma unroll
        for (int e = 0; e < NEXP; ++e) out[OUT_PROBS + (size_t)t * NEXP + e] = p[e];
        out[OUT_IDX + (size_t)t * TOPK + 0] = (float)i0;
        out[OUT_IDX + (size_t)t * TOPK + 1] = (float)i1;
        out[OUT_W + (size_t)t * TOPK + 0] = w0n;
        out[OUT_W + (size_t)t * TOPK + 1] = w1n;
        tok_e[t * 2 + 0] = i0;
        tok_e[t * 2 + 1] = i1;
        tok_w[t * 2 + 0] = w0n;
        tok_w[t * 2 + 1] = w1n;
    }
}

// ---------------- Finalize: histogram, 128-padded offsets, slot assignment ----------------
__global__ void k_finalize(const int* __restrict__ tok_e, const float* __restrict__ tok_w,
                           int* __restrict__ offs, int* __restrict__ row_tok,
                           float* __restrict__ slot_w) {
    __shared__ int cnt[NEXP];
    __shared__ int fill[NEXP];
    __shared__ int soff[NEXP + 1];
    const int tid = threadIdx.x;
    if (tid < NEXP) { cnt[tid] = 0; fill[tid] = 0; }
    __syncthreads();
    for (int i = tid; i < TOKENS * 2; i += 256) atomicAdd(&cnt[tok_e[i]], 1);
    __syncthreads();
    if (tid == 0) {
        int o = 0;
        for (int e = 0; e < NEXP; ++e) {
            soff[e] = o;
            o += (cnt[e] + 127) & ~127;  // pad to tile multiple: tiles never straddle experts
        }
        soff[NEXP] = o;
    }
    __syncthreads();
    if (tid <= NEXP) offs[tid] = soff[tid];
    for (int i = tid; i < MAXSLOTS; i += 256) { row_tok[i] = -1; slot_w[i] = 0.f; }
    __syncthreads();
    for (int i = tid; i < TOKENS * 2; i += 256) {
        int e = tok_e[i];
        int pos = atomicAdd(&fill[e], 1);
        int slot = soff[e] + pos;
        row_tok[slot] = i >> 1;
        slot_w[slot] = tok_w[i];
    }
}

// ---------------- GEMM1: H = silu(x_gathered @ w1_e^T), BM=128 BN=64 BK=32 ----------------
__global__ __launch_bounds__(256) void k_gemm1(
        const float* __restrict__ x, const float* __restrict__ w1,
        const int* __restrict__ offs, const int* __restrict__ row_tok,
        bf16_t* __restrict__ H) {
    const int m0 = blockIdx.y * 128;            // GLOBAL slot-tile (tiles are 128-aligned per expert)
    if (m0 >= offs[NEXP]) return;
    int e = 0;
    while (m0 >= offs[e + 1]) ++e;              // which expert owns this tile
    const int n0 = blockIdx.x * 64;

    __shared__ __align__(16) bf16_t As[128 * LDSW];
    __shared__ __align__(16) bf16_t Bs[64 * LDSW];
    __shared__ int rtok[128];

    const int tid = threadIdx.x;
    if (tid < 128) rtok[tid] = row_tok[m0 + tid];
    __syncthreads();

    const int wid = tid >> 6, lane = tid & 63;
    const int wr = wid >> 1, wc = wid & 1;      // wave tile: 64 rows x 32 cols
    const int lr = lane & 15, ls = lane >> 4;

    f32x4 acc[4][2];
#pragma unroll
    for (int mi = 0; mi < 4; ++mi)
#pragma unroll
        for (int ni = 0; ni < 2; ++ni) acc[mi][ni] = (f32x4){0.f, 0.f, 0.f, 0.f};

    const int rA = tid >> 1, hA = tid & 1;      // A staging: 128 rows x 2 halves (16 f32 each)
    const int rB = tid >> 2, qB = tid & 3;      // B staging: 64 rows x 4 quarters (8 f32 each)
    const int tA = rtok[rA];
    const float* xrow = x + (size_t)(tA < 0 ? 0 : tA) * DMODEL;
    const float* wrow = w1 + ((size_t)e * FFDIM + n0 + rB) * DMODEL;

    float4 ar[4], br[2];
    const int NK = DMODEL / 32;

#define G1_LOAD(k0)                                                        \
    {                                                                      \
        if (tA >= 0) {                                                     \
            const float4* p = (const float4*)(xrow + (k0) + hA * 16);      \
            ar[0] = p[0]; ar[1] = p[1]; ar[2] = p[2]; ar[3] = p[3];        \
        } else {                                                           \
            ar[0] = ar[1] = ar[2] = ar[3] = (float4){0.f, 0.f, 0.f, 0.f};  \
        }                                                                  \
        const float4* q = (const float4*)(wrow + (k0) + qB * 8);           \
        br[0] = q[0]; br[1] = q[1];                                        \
    }

    G1_LOAD(0);
    for (int kt = 0; kt < NK; ++kt) {
        // stage current regs (f32 -> bf16) into padded LDS
        {
            bf16x8 v0, v1, w;
            v0[0] = (bf16_t)ar[0].x; v0[1] = (bf16_t)ar[0].y; v0[2] = (bf16_t)ar[0].z; v0[3] = (bf16_t)ar[0].w;
            v0[4] = (bf16_t)ar[1].x; v0[5] = (bf16_t)ar[1].y; v0[6] = (bf16_t)ar[1].z; v0[7] = (bf16_t)ar[1].w;
            v1[0] = (bf16_t)ar[2].x; v1[1] = (bf16_t)ar[2].y; v1[2] = (bf16_t)ar[2].z; v1[3] = (bf16_t)ar[2].w;
            v1[4] = (bf16_t)ar[3].x; v1[5] = (bf16_t)ar[3].y; v1[6] = (bf16_t)ar[3].z; v1[7] = (bf16_t)ar[3].w;
            w[0] = (bf16_t)br[0].x; w[1] = (bf16_t)br[0].y; w[2] = (bf16_t)br[0].z; w[3] = (bf16_t)br[0].w;
            w[4] = (bf16_t)br[1].x; w[5] = (bf16_t)br[1].y; w[6] = (bf16_t)br[1].z; w[7] = (bf16_t)br[1].w;
            *(bf16x8*)&As[rA * LDSW + hA * 16] = v0;
            *(bf16x8*)&As[rA * LDSW + hA * 16 + 8] = v1;
            *(bf16x8*)&Bs[rB * LDSW + qB * 8] = w;
        }
        __syncthreads();
        if (kt + 1 < NK) G1_LOAD((kt + 1) * 32);
        bf16x8 af[4], bv[2];
#pragma unroll
        for (int mi = 0; mi < 4; ++mi)
            af[mi] = *(const bf16x8*)&As[(wr * 64 + mi * 16 + lr) * LDSW + ls * 8];
#pragma unroll
        for (int ni = 0; ni < 2; ++ni)
            bv[ni] = *(const bf16x8*)&Bs[(wc * 32 + ni * 16 + lr) * LDSW + ls * 8];
#pragma unroll
        for (int mi = 0; mi < 4; ++mi)
#pragma unroll
            for (int ni = 0; ni < 2; ++ni)
                acc[mi][ni] = __builtin_amdgcn_mfma_f32_16x16x32_bf16(af[mi], bv[ni], acc[mi][ni], 0, 0, 0);
        __syncthreads();
    }
#undef G1_LOAD

    // epilogue: SiLU, store bf16 H  (C/D map: col=lane&15, row=(lane>>4)*4+reg)
#pragma unroll
    for (int mi = 0; mi < 4; ++mi) {
#pragma unroll
        for (int ni = 0; ni < 2; ++ni) {
            const int colL = n0 + wc * 32 + ni * 16 + lr;
#pragma unroll
            for (int v = 0; v < 4; ++v) {
                const int rowL = wr * 64 + mi * 16 + ls * 4 + v;
                float val = acc[mi][ni][v];
                float sv = val / (1.f + expf(-val));
                H[(size_t)(m0 + rowL) * FFDIM + colL] = (bf16_t)sv;
            }
        }
    }
}

// ---------------- GEMM2: out[tok] += w_slot * (H @ w2_e^T), split-K=2, atomic scatter ----------------
__global__ __launch_bounds__(256) void k_gemm2(
        const bf16_t* __restrict__ H, const float* __restrict__ w2,
        const int* __restrict__ offs, const int* __restrict__ row_tok,
        const float* __restrict__ slot_w, float* __restrict__ out) {
    const int m0 = blockIdx.y * 128;
    if (m0 >= offs[NEXP]) return;
    int e = 0;
    while (m0 >= offs[e + 1]) ++e;
    const int n0 = blockIdx.x * 64;
    const int kbase = blockIdx.z * (FFDIM / 2);  // split-K=2

    __shared__ __align__(16) bf16_t As[128 * LDSW];
    __shared__ __align__(16) bf16_t Bs[64 * LDSW];
    __shared__ int rtok[128];
    __shared__ float swt[128];

    const int tid = threadIdx.x;
    if (tid < 128) { rtok[tid] = row_tok[m0 + tid]; swt[tid] = slot_w[m0 + tid]; }

    const int wid = tid >> 6, lane = tid & 63;
    const int wr = wid >> 1, wc = wid & 1;
    const int lr = lane & 15, ls = lane >> 4;

    f32x4 acc[4][2];
#pragma unroll
    for (int mi = 0; mi < 4; ++mi)
#pragma unroll
        for (int ni = 0; ni < 2; ++ni) acc[mi][ni] = (f32x4){0.f, 0.f, 0.f, 0.f};

    const int rA = tid >> 1, hA = tid & 1;
    const int rB = tid >> 2, qB = tid & 3;
    const bf16_t* hrow = H + (size_t)(m0 + rA) * FFDIM + kbase;
    const float* wrow = w2 + ((size_t)e * DMODEL + n0 + rB) * FFDIM + kbase;

    float4 ar[2], br[2];
    const int NK = (FFDIM / 2) / 32;  // 32 k-steps per split

#define G2_LOAD(k0)                                                   \
    {                                                                 \
        const float4* p = (const float4*)(hrow + (k0) + hA * 16);     \
        ar[0] = p[0]; ar[1] = p[1];                                   \
        const float4* q = (const float4*)(wrow + (k0) + qB * 8);      \
        br[0] = q[0]; br[1] = q[1];                                   \
    }

    G2_LOAD(0);
    for (int kt = 0; kt < NK; ++kt) {
        {
            bf16x8 w;
            w[0] = (bf16_t)br[0].x; w[1] = (bf16_t)br[0].y; w[2] = (bf16_t)br[0].z; w[3] = (bf16_t)br[0].w;
            w[4] = (bf16_t)br[1].x; w[5] = (bf16_t)br[1].y; w[6] = (bf16_t)br[1].z; w[7] = (bf16_t)br[1].w;
            *(float4*)&As[rA * LDSW + hA * 16] = ar[0];   // already bf16 bits
            *(float4*)&As[rA * LDSW + hA * 16 + 8] = ar[1];
            *(bf16x8*)&Bs[rB * LDSW + qB * 8] = w;
        }
        __syncthreads();
        if (kt + 1 < NK) G2_LOAD((kt + 1) * 32);
        bf16x8 af[4], bv[2];
#pragma unroll
        for (int mi = 0; mi < 4; ++mi)
            af[mi] = *(const bf16x8*)&As[(wr * 64 + mi * 16 + lr) * LDSW + ls * 8];
#pragma unroll
        for (int ni = 0; ni < 2; ++ni)
            bv[ni] = *(const bf16x8*)&Bs[(wc * 32 + ni * 16 + lr) * LDSW + ls * 8];
#pragma unroll
        for (int mi = 0; mi < 4; ++mi)
#pragma unroll
            for (int ni = 0; ni < 2; ++ni)
                acc[mi][ni] = __builtin_amdgcn_mfma_f32_16x16x32_bf16(af[mi], bv[ni], acc[mi][ni], 0, 0, 0);
        __syncthreads();
    }
#undef G2_LOAD

    // epilogue: scatter-accumulate into out (zeroed by memset); fuses combine
#pragma unroll
    for (int mi = 0; mi < 4; ++mi) {
#pragma unroll
        for (int v = 0; v < 4; ++v) {
            const int rowL = wr * 64 + mi * 16 + ls * 4 + v;
            const int tok = rtok[rowL];
            if (tok < 0) continue;
            const float wgt = swt[rowL];
            float* orow = out + (size_t)tok * DMODEL + n0;
#pragma unroll
            for (int ni = 0; ni < 2; ++ni) {
                const int colL = wc * 32 + ni * 16 + lr;
                atomicAdd(orow + colL, wgt * acc[mi][ni][v]);
            }
        }
    }
}

extern "C" void kernel_launch(void* const* d_in, const int* in_sizes, int n_in,
                              void* d_out, int out_size, void* d_ws, size_t ws_size,
                              hipStream_t stream) {
    const float* x = (const float*)d_in[0];
    const float* rw = (const float*)d_in[1];
    const float* w1 = (const float*)d_in[2];
    const float* w2 = (const float*)d_in[3];
    float* out = (float*)d_out;
    char* ws = (char*)d_ws;

    int* tok_e = (int*)(ws + WS_TOKE);
    float* tok_w = (float*)(ws + WS_TOKW);
    int* offs = (int*)(ws + WS_OFFS);
    int* row_tok = (int*)(ws + WS_ROWTOK);
    float* slot_w = (float*)(ws + WS_SLOTW);
    bf16_t* H = (bf16_t*)(ws + WS_H);

    hipMemsetAsync(out, 0, (size_t)OUT_PROBS * sizeof(float), stream);  // gemm2 accumulates into out
    k_router<<<TOKENS / 4, 256, 0, stream>>>(x, rw, out, tok_e, tok_w);
    k_finalize<<<1, 256, 0, stream>>>(tok_e, tok_w, offs, row_tok, slot_w);
    k_gemm1<<<dim3(FFDIM / 64, MTILES), 256, 0, stream>>>(x, w1, offs, row_tok, H);
    k_gemm2<<<dim3(DMODEL / 64, MTILES, 2), 256, 0, stream>>>(H, w2, offs, row_tok, slot_w, out);
}

// Round 3
// 254.856 us; speedup vs baseline: 1.5347x; 1.4042x over previous
//
#include <hip/hip_runtime.h>
#include <hip/hip_bf16.h>

// Problem constants
#define TOKENS 2048      // B*S
#define DMODEL 1024
#define NEXP 8
#define TOPK 2
#define FFDIM 2048
#define MAXSLOTS 5120    // sum of per-expert 128-padded counts <= 4096 + 8*127
#define MTILES (MAXSLOTS / 128)   // 40

typedef __bf16 bf16_t;
typedef __bf16 bf16x8 __attribute__((ext_vector_type(8)));
typedef __bf16 bf16x4 __attribute__((ext_vector_type(4)));
typedef float f32x4 __attribute__((ext_vector_type(4)));

// d_out layout (floats): output | router_probs | topk_indices | topk_weights
#define OUT_PROBS (TOKENS * DMODEL)
#define OUT_IDX (OUT_PROBS + TOKENS * NEXP)
#define OUT_W (OUT_IDX + TOKENS * TOPK)

// ws layout (bytes)
#define WS_TOKE 0                 // int[4096]
#define WS_TOKW 16384             // float[4096]
#define WS_OFFS 32768             // int[16]
#define WS_ROWTOK 33024           // int[5120]
#define WS_SLOTOF 53504           // int[4096]
#define WS_XB 131072              // bf16 [2048][1024]        -> ends 4325376
#define WS_H 4325376              // bf16 [5120][2048]        -> ends 25296896
#define WS_Y 25296896             // bf16 [5120][1024]        -> ends 35782656
#define WS_WB 35782656            // bf16 [16777216] (w1b, then w2b) -> ends 69337088

// async global->LDS, 16B per lane. LDS dest must be wave-uniform base (+lane*16 by HW).
__device__ __forceinline__ void async16(const bf16_t* g, bf16_t* l) {
    __builtin_amdgcn_global_load_lds(
        (const __attribute__((address_space(1))) unsigned int*)g,
        (__attribute__((address_space(3))) unsigned int*)l, 16, 0, 0);
}

// ---------------- cast f32 -> bf16 (8 elems/thread) ----------------
__global__ __launch_bounds__(256) void k_cast(const float* __restrict__ src,
                                              bf16_t* __restrict__ dst) {
    const size_t i = ((size_t)blockIdx.x * 256 + threadIdx.x) * 8;
    float4 a = *(const float4*)&src[i];
    float4 b = *(const float4*)&src[i + 4];
    bf16x8 v;
    v[0] = (bf16_t)a.x; v[1] = (bf16_t)a.y; v[2] = (bf16_t)a.z; v[3] = (bf16_t)a.w;
    v[4] = (bf16_t)b.x; v[5] = (bf16_t)b.y; v[6] = (bf16_t)b.z; v[7] = (bf16_t)b.w;
    *(bf16x8*)&dst[i] = v;
}

// ---------------- Router: logits, softmax, top-2, renorm; also emits x as bf16 ----------------
__global__ __launch_bounds__(256) void k_router(
        const float* __restrict__ x, const float* __restrict__ rw,
        float* __restrict__ out, int* __restrict__ tok_e, float* __restrict__ tok_w,
        bf16_t* __restrict__ xb) {
    __shared__ float s_rw[NEXP * DMODEL];  // 32 KB
    const float4* rw4 = (const float4*)rw;
    float4* s4 = (float4*)s_rw;
#pragma unroll
    for (int i = 0; i < (NEXP * DMODEL / 4) / 256; ++i)
        s4[i * 256 + threadIdx.x] = rw4[i * 256 + threadIdx.x];
    __syncthreads();

    const int wave = threadIdx.x >> 6;
    const int lane = threadIdx.x & 63;
    const int t = blockIdx.x * 4 + wave;  // one wave per token

    float acc[NEXP];
#pragma unroll
    for (int e = 0; e < NEXP; ++e) acc[e] = 0.f;
    const float4* xr = (const float4*)(x + (size_t)t * DMODEL);
#pragma unroll
    for (int j = 0; j < DMODEL / 256; ++j) {  // 4 steps, float4 per lane
        float4 xv = xr[j * 64 + lane];
        bf16x4 xc;
        xc[0] = (bf16_t)xv.x; xc[1] = (bf16_t)xv.y; xc[2] = (bf16_t)xv.z; xc[3] = (bf16_t)xv.w;
        *(bf16x4*)&xb[(size_t)t * DMODEL + (j * 64 + lane) * 4] = xc;
#pragma unroll
        for (int e = 0; e < NEXP; ++e) {
            const float4 rv = *(const float4*)&s_rw[e * DMODEL + (j * 64 + lane) * 4];
            acc[e] += xv.x * rv.x + xv.y * rv.y + xv.z * rv.z + xv.w * rv.w;
        }
    }
#pragma unroll
    for (int off = 32; off > 0; off >>= 1) {
#pragma unroll
        for (int e = 0; e < NEXP; ++e) acc[e] += __shfl_xor(acc[e], off);
    }

    if (lane == 0) {
        float m = acc[0];
#pragma unroll
        for (int e = 1; e < NEXP; ++e) m = fmaxf(m, acc[e]);
        float p[NEXP];
        float sum = 0.f;
#pragma unroll
        for (int e = 0; e < NEXP; ++e) { p[e] = expf(acc[e] - m); sum += p[e]; }
#pragma unroll
        for (int e = 0; e < NEXP; ++e) p[e] = p[e] / sum;
        int i0 = 0;
#pragma unroll
        for (int e = 1; e < NEXP; ++e) if (p[e] > p[i0]) i0 = e;
        int i1 = (i0 == 0) ? 1 : 0;
#pragma unroll
        for (int e = 0; e < NEXP; ++e) if (e != i0 && p[e] > p[i1]) i1 = e;
        float w0 = p[i0], w1 = p[i1];
        float s2 = w0 + w1;
        float w0n = w0 / s2, w1n = w1 / s2;
#pragma unroll
        for (int e = 0; e < NEXP; ++e) out[OUT_PROBS + (size_t)t * NEXP + e] = p[e];
        out[OUT_IDX + (size_t)t * TOPK + 0] = (float)i0;
        out[OUT_IDX + (size_t)t * TOPK + 1] = (float)i1;
        out[OUT_W + (size_t)t * TOPK + 0] = w0n;
        out[OUT_W + (size_t)t * TOPK + 1] = w1n;
        tok_e[t * 2 + 0] = i0;
        tok_e[t * 2 + 1] = i1;
        tok_w[t * 2 + 0] = w0n;
        tok_w[t * 2 + 1] = w1n;
    }
}

// ---------------- Finalize: histogram, 128-padded offsets, slot assignment ----------------
__global__ void k_finalize(const int* __restrict__ tok_e,
                           int* __restrict__ offs, int* __restrict__ row_tok,
                           int* __restrict__ slot_of) {
    __shared__ int cnt[NEXP];
    __shared__ int fill[NEXP];
    __shared__ int soff[NEXP + 1];
    const int tid = threadIdx.x;
    if (tid < NEXP) { cnt[tid] = 0; fill[tid] = 0; }
    __syncthreads();
    for (int i = tid; i < TOKENS * 2; i += 256) atomicAdd(&cnt[tok_e[i]], 1);
    __syncthreads();
    if (tid == 0) {
        int o = 0;
        for (int e = 0; e < NEXP; ++e) {
            soff[e] = o;
            o += (cnt[e] + 127) & ~127;  // tiles never straddle experts
        }
        soff[NEXP] = o;
    }
    __syncthreads();
    if (tid <= NEXP) offs[tid] = soff[tid];
    for (int i = tid; i < MAXSLOTS; i += 256) row_tok[i] = -1;
    __syncthreads();
    for (int i = tid; i < TOKENS * 2; i += 256) {
        int e = tok_e[i];
        int pos = atomicAdd(&fill[e], 1);
        int slot = soff[e] + pos;
        row_tok[slot] = i >> 1;
        slot_of[i] = slot;
    }
}

// ---------------- GEMM1: H = silu(x_gathered @ w1_e^T) ----------------
// BM=128 BN=128 BK=64, 256 thr, 4 waves (2x2 of 64x64), global_load_lds + XOR swizzle.
// LDS rows are 128B; stored[r][j] = logical[r][j^(r&7)] (16B slots). Writer pre-swizzles
// the GLOBAL source (T21); reader XORs the slot. 16-lane frag reads: 8 bank-groups x 2 = free.
__global__ __launch_bounds__(256, 2) void k_gemm1(
        const bf16_t* __restrict__ xb, const bf16_t* __restrict__ w1b,
        const int* __restrict__ offs, const int* __restrict__ row_tok,
        bf16_t* __restrict__ H) {
    const int m0 = blockIdx.y * 128;
    if (m0 >= offs[NEXP]) return;
    int e = 0;
    while (m0 >= offs[e + 1]) ++e;
    const int n0 = blockIdx.x * 128;

    __shared__ __align__(16) bf16_t As[2][128 * 64];  // 16KB each buf
    __shared__ __align__(16) bf16_t Bs[2][128 * 64];

    const int tid = threadIdx.x;
    const int wid = tid >> 6, lane = tid & 63;
    const int wr = wid >> 1, wc = wid & 1;
    const int lr = lane & 15, ls = lane >> 4;

    // staging: 8 lanes/row (16B each), 32 rows per instr, 4 instrs per operand
    const int rq = tid >> 3;                // 0..31
    const int jx = (tid & 7) ^ (rq & 7);    // pre-swizzled 16B slot within 128B row
    const bf16_t* asrc[4];
    const bf16_t* bsrc[4];
#pragma unroll
    for (int q = 0; q < 4; ++q) {
        const int r = q * 32 + rq;
        int tok = row_tok[m0 + r];
        if (tok < 0) tok = 0;  // pad rows compute garbage; never combined
        asrc[q] = xb + (size_t)tok * DMODEL + jx * 8;
        bsrc[q] = w1b + ((size_t)e * FFDIM + n0 + r) * DMODEL + jx * 8;
    }

    f32x4 acc[4][4];
#pragma unroll
    for (int mi = 0; mi < 4; ++mi)
#pragma unroll
        for (int ni = 0; ni < 4; ++ni) acc[mi][ni] = (f32x4){0.f, 0.f, 0.f, 0.f};

    const int NK = DMODEL / 64;  // 16

#define STAGE1(b, kt)                                      \
    {                                                      \
        bf16_t* Ad = &As[b][wid * 512];                    \
        bf16_t* Bd = &Bs[b][wid * 512];                    \
        _Pragma("unroll") for (int q = 0; q < 4; ++q) {    \
            async16(asrc[q] + (kt) * 64, Ad + q * 2048);   \
            async16(bsrc[q] + (kt) * 64, Bd + q * 2048);   \
        }                                                  \
    }

    int buf = 0;
    STAGE1(0, 0);
    __syncthreads();
    for (int kt = 0; kt < NK; ++kt) {
        if (kt + 1 < NK) STAGE1(buf ^ 1, kt + 1);  // in flight across compute
#pragma unroll
        for (int kk = 0; kk < 2; ++kk) {
            const int sA = ((kk << 2) + ls) ^ (lr & 7);
            bf16x8 af[4], bv[4];
#pragma unroll
            for (int mi = 0; mi < 4; ++mi)
                af[mi] = *(const bf16x8*)&As[buf][(wr * 64 + mi * 16 + lr) * 64 + sA * 8];
#pragma unroll
            for (int ni = 0; ni < 4; ++ni)
                bv[ni] = *(const bf16x8*)&Bs[buf][(wc * 64 + ni * 16 + lr) * 64 + sA * 8];
#pragma unroll
            for (int mi = 0; mi < 4; ++mi)
#pragma unroll
                for (int ni = 0; ni < 4; ++ni)
                    acc[mi][ni] = __builtin_amdgcn_mfma_f32_16x16x32_bf16(af[mi], bv[ni], acc[mi][ni], 0, 0, 0);
        }
        __syncthreads();  // drains vmcnt(0): next tile staged, this buf free
        buf ^= 1;
    }
#undef STAGE1

    // epilogue: SiLU -> H (C/D map: col=lane&15, row=(lane>>4)*4+reg)
#pragma unroll
    for (int mi = 0; mi < 4; ++mi) {
        const int rowL = m0 + wr * 64 + mi * 16 + ls * 4;
#pragma unroll
        for (int ni = 0; ni < 4; ++ni) {
            const int colL = n0 + wc * 64 + ni * 16 + lr;
#pragma unroll
            for (int v = 0; v < 4; ++v) {
                float val = acc[mi][ni][v];
                H[(size_t)(rowL + v) * FFDIM + colL] = (bf16_t)(val / (1.f + expf(-val)));
            }
        }
    }
}

// ---------------- GEMM2: Y = H @ w2_e^T (bf16 out, slot-major, no atomics) ----------------
// BM=128 BN=64 BK=64: 576 real blocks.
__global__ __launch_bounds__(256, 3) void k_gemm2(
        const bf16_t* __restrict__ H, const bf16_t* __restrict__ w2b,
        const int* __restrict__ offs, bf16_t* __restrict__ Y) {
    const int m0 = blockIdx.y * 128;
    if (m0 >= offs[NEXP]) return;
    int e = 0;
    while (m0 >= offs[e + 1]) ++e;
    const int n0 = blockIdx.x * 64;

    __shared__ __align__(16) bf16_t As[2][128 * 64];  // 16KB each
    __shared__ __align__(16) bf16_t Bs[2][64 * 64];   // 8KB each

    const int tid = threadIdx.x;
    const int wid = tid >> 6, lane = tid & 63;
    const int wr = wid >> 1, wc = wid & 1;
    const int lr = lane & 15, ls = lane >> 4;

    const int rq = tid >> 3;
    const int jx = (tid & 7) ^ (rq & 7);
    const bf16_t* asrc[4];
    const bf16_t* bsrc[2];
#pragma unroll
    for (int q = 0; q < 4; ++q)
        asrc[q] = H + (size_t)(m0 + q * 32 + rq) * FFDIM + jx * 8;
#pragma unroll
    for (int q = 0; q < 2; ++q)
        bsrc[q] = w2b + ((size_t)e * DMODEL + n0 + q * 32 + rq) * FFDIM + jx * 8;

    f32x4 acc[4][2];
#pragma unroll
    for (int mi = 0; mi < 4; ++mi)
#pragma unroll
        for (int ni = 0; ni < 2; ++ni) acc[mi][ni] = (f32x4){0.f, 0.f, 0.f, 0.f};

    const int NK = FFDIM / 64;  // 32

#define STAGE2(b, kt)                                      \
    {                                                      \
        bf16_t* Ad = &As[b][wid * 512];                    \
        bf16_t* Bd = &Bs[b][wid * 512];                    \
        _Pragma("unroll") for (int q = 0; q < 4; ++q)      \
            async16(asrc[q] + (kt) * 64, Ad + q * 2048);   \
        _Pragma("unroll") for (int q = 0; q < 2; ++q)      \
            async16(bsrc[q] + (kt) * 64, Bd + q * 2048);   \
    }

    int buf = 0;
    STAGE2(0, 0);
    __syncthreads();
    for (int kt = 0; kt < NK; ++kt) {
        if (kt + 1 < NK) STAGE2(buf ^ 1, kt + 1);
#pragma unroll
        for (int kk = 0; kk < 2; ++kk) {
            const int sA = ((kk << 2) + ls) ^ (lr & 7);
            bf16x8 af[4], bv[2];
#pragma unroll
            for (int mi = 0; mi < 4; ++mi)
                af[mi] = *(const bf16x8*)&As[buf][(wr * 64 + mi * 16 + lr) * 64 + sA * 8];
#pragma unroll
            for (int ni = 0; ni < 2; ++ni)
                bv[ni] = *(const bf16x8*)&Bs[buf][(wc * 32 + ni * 16 + lr) * 64 + sA * 8];
#pragma unroll
            for (int mi = 0; mi < 4; ++mi)
#pragma unroll
                for (int ni = 0; ni < 2; ++ni)
                    acc[mi][ni] = __builtin_amdgcn_mfma_f32_16x16x32_bf16(af[mi], bv[ni], acc[mi][ni], 0, 0, 0);
        }
        __syncthreads();
        buf ^= 1;
    }
#undef STAGE2

#pragma unroll
    for (int mi = 0; mi < 4; ++mi) {
        const int rowL = m0 + wr * 64 + mi * 16 + ls * 4;
#pragma unroll
        for (int ni = 0; ni < 2; ++ni) {
            const int colL = n0 + wc * 32 + ni * 16 + lr;
#pragma unroll
            for (int v = 0; v < 4; ++v)
                Y[(size_t)(rowL + v) * DMODEL + colL] = (bf16_t)acc[mi][ni][v];
        }
    }
}

// ---------------- Combine: out[t] = w0*Y[s0] + w1*Y[s1] ----------------
__global__ __launch_bounds__(256) void k_combine(
        const bf16_t* __restrict__ Y, const int* __restrict__ slot_of,
        const float* __restrict__ tok_w, float* __restrict__ out) {
    const int t = blockIdx.x;
    const int c = threadIdx.x * 4;
    const int s0 = slot_of[t * 2 + 0], s1 = slot_of[t * 2 + 1];
    const float w0 = tok_w[t * 2 + 0], w1 = tok_w[t * 2 + 1];
    bf16x4 y0 = *(const bf16x4*)&Y[(size_t)s0 * DMODEL + c];
    bf16x4 y1 = *(const bf16x4*)&Y[(size_t)s1 * DMODEL + c];
    float4 o;
    o.x = w0 * (float)y0[0] + w1 * (float)y1[0];
    o.y = w0 * (float)y0[1] + w1 * (float)y1[1];
    o.z = w0 * (float)y0[2] + w1 * (float)y1[2];
    o.w = w0 * (float)y0[3] + w1 * (float)y1[3];
    *(float4*)&out[(size_t)t * DMODEL + c] = o;
}

extern "C" void kernel_launch(void* const* d_in, const int* in_sizes, int n_in,
                              void* d_out, int out_size, void* d_ws, size_t ws_size,
                              hipStream_t stream) {
    const float* x = (const float*)d_in[0];
    const float* rw = (const float*)d_in[1];
    const float* w1 = (const float*)d_in[2];
    const float* w2 = (const float*)d_in[3];
    float* out = (float*)d_out;
    char* ws = (char*)d_ws;

    int* tok_e = (int*)(ws + WS_TOKE);
    float* tok_w = (float*)(ws + WS_TOKW);
    int* offs = (int*)(ws + WS_OFFS);
    int* row_tok = (int*)(ws + WS_ROWTOK);
    int* slot_of = (int*)(ws + WS_SLOTOF);
    bf16_t* xb = (bf16_t*)(ws + WS_XB);
    bf16_t* H = (bf16_t*)(ws + WS_H);
    bf16_t* Yb = (bf16_t*)(ws + WS_Y);
    bf16_t* wb = (bf16_t*)(ws + WS_WB);  // shared: w1b during gemm1, w2b during gemm2

    const int WCAST_BLOCKS = (NEXP * FFDIM * DMODEL) / (8 * 256);  // 8192

    k_router<<<TOKENS / 4, 256, 0, stream>>>(x, rw, out, tok_e, tok_w, xb);
    k_finalize<<<1, 256, 0, stream>>>(tok_e, offs, row_tok, slot_of);
    k_cast<<<WCAST_BLOCKS, 256, 0, stream>>>(w1, wb);
    k_gemm1<<<dim3(FFDIM / 128, MTILES), 256, 0, stream>>>(xb, wb, offs, row_tok, H);
    k_cast<<<WCAST_BLOCKS, 256, 0, stream>>>(w2, wb);  // reuse buffer after gemm1
    k_gemm2<<<dim3(DMODEL / 64, MTILES), 256, 0, stream>>>(H, wb, offs, Yb);
    k_combine<<<TOKENS, 256, 0, stream>>>(Yb, slot_of, tok_w, out);
}